// Round 9
// baseline (316.001 us; speedup 1.0000x reference)
//
#include <hip/hip_runtime.h>
#include <hip/hip_bf16.h>
#include <math.h>

// Problem constants
#define N1R 65536   // B*N1 query rows
#define N2R 16384   // B*N2 point rows
#define NPB 4096    // N2 per batch
#define NQB 16384   // N1 per batch
#define CC  256     // COUT
#define ASTRIDE 40  // LDS A-tile row stride in bf16 elems (80B: 16B-aligned, ~2-way banks)
#define NCELL 512   // 8x8x8 grid cells per batch
#define GRID_FAIL_R2 0.015625f   // (1/8)^2 coverage bound of the 27-cell block

typedef __attribute__((ext_vector_type(4))) float v4f;
typedef __attribute__((ext_vector_type(8))) short v8s;

static __device__ __forceinline__ short f2bs(float f) {
    union { __hip_bfloat16 h; short s; } u;
    u.h = __float2bfloat16(f);
    return u.s;
}

static __device__ __forceinline__ int cell_of(float x, float y, float z) {
    const int cx = min(7, (int)(x * 8.0f));
    const int cy = min(7, (int)(y * 8.0f));
    const int cz = min(7, (int)(z * 8.0f));
    return (cz << 6) | (cy << 3) | cx;
}

// branchless lexicographic (d, idx) top-3 insert; keeps b0<=b1<=b2 sorted
static __device__ __forceinline__ void ins3(float d, int si,
    float& b0, float& b1, float& b2, int& i0, int& i1, int& i2)
{
    const bool lt0 = (d < b0) | ((d == b0) & (si < i0));
    const bool lt1 = (d < b1) | ((d == b1) & (si < i1));
    const bool lt2 = (d < b2) | ((d == b2) & (si < i2));
    b2 = lt1 ? b1 : (lt2 ? d : b2);   i2 = lt1 ? i1 : (lt2 ? si : i2);
    b1 = lt0 ? b0 : (lt1 ? d : b1);   i1 = lt0 ? i0 : (lt1 ? si : i1);
    b0 = lt0 ? d  : b0;               i0 = lt0 ? si : i0;
}

// ---------------------------------------------------------------------------
// Merged prep: W transposes + paug + both cell histograms in ONE launch.
// blocks 0..767  : WT[n][k] = bf16(W[k][n]) for W1 then W2
// blocks 768..831: paug + point histogram (exact fp32, no FMA)
// blocks 832..1087: query histogram
// ---------------------------------------------------------------------------
__global__ __launch_bounds__(256)
void prep_kernel(const float* __restrict__ W1f, const float* __restrict__ W2f,
                 short* __restrict__ WT1, short* __restrict__ WT2,
                 const float* __restrict__ p2, const float* __restrict__ p1,
                 float4* __restrict__ paug,
                 int* __restrict__ counts_p, int* __restrict__ counts_q)
{
#pragma clang fp contract(off)
    const int bid = blockIdx.x;
    if (bid < 768) {
        const int i = bid * 256 + threadIdx.x;   // 0 .. 196607
        if (i < 65536) {
            const int k = i >> 8, n = i & 255;
            WT1[(size_t)n * 256 + k] = f2bs(W1f[i]);
        } else {
            const int j = i - 65536;
            const int k = j >> 8, n = j & 255;
            WT2[(size_t)n * 512 + k] = f2bs(W2f[j]);
        }
    } else if (bid < 832) {
        const int i = (bid - 768) * 256 + threadIdx.x;   // over N2R
        const float x = p2[(size_t)i * 3 + 0];
        const float y = p2[(size_t)i * 3 + 1];
        const float z = p2[(size_t)i * 3 + 2];
        float4 v;
        v.x = x; v.y = y; v.z = z;
        v.w = (x * x + y * y) + z * z;
        paug[i] = v;
        const int b = i >> 12;
        atomicAdd(&counts_p[b * NCELL + cell_of(x, y, z)], 1);
    } else {
        const int i = (bid - 832) * 256 + threadIdx.x;   // over N1R
        const float x = p1[(size_t)i * 3 + 0];
        const float y = p1[(size_t)i * 3 + 1];
        const float z = p1[(size_t)i * 3 + 2];
        const int b = i >> 14;
        atomicAdd(&counts_q[b * NCELL + cell_of(x, y, z)], 1);
    }
}

// ---------------------------------------------------------------------------
// Exclusive prefix over 512 cells, 4 batches x {points, queries}.
// Wave-shuffle Hillis-Steele scan: 3 syncthreads/pass.
// ---------------------------------------------------------------------------
__global__ __launch_bounds__(512)
void prefix_kernel(const int* __restrict__ counts_p, int* __restrict__ cursors_p,
                   int* __restrict__ starts_p,
                   const int* __restrict__ counts_q, int* __restrict__ cursors_q)
{
    __shared__ int sw[8];      // per-wave totals
    __shared__ int sbase[8];   // per-wave exclusive bases
    const int t = threadIdx.x;
    const int lane = t & 63, wid = t >> 6;
    for (int a = 0; a < 8; ++a) {
        const int b = a & 3;
        const int* cnt = (a < 4) ? counts_p + b * NCELL : counts_q + b * NCELL;
        const int v = cnt[t];
        int incl = v;
#pragma unroll
        for (int off = 1; off < 64; off <<= 1) {
            const int u = __shfl_up(incl, off);
            incl += (lane >= off) ? u : 0;
        }
        if (lane == 63) sw[wid] = incl;
        __syncthreads();
        if (t == 0) {
            int s = 0;
#pragma unroll
            for (int w = 0; w < 8; ++w) { const int x = sw[w]; sbase[w] = s; s += x; }
        }
        __syncthreads();
        const int inclT = incl + sbase[wid];
        const int excl = inclT - v;
        if (a < 4) {
            starts_p[b * 513 + t] = excl;
            if (t == 511) starts_p[b * 513 + 512] = inclT;   // == 4096
            cursors_p[b * NCELL + t] = excl;
        } else {
            cursors_q[b * NCELL + t] = excl;
        }
        __syncthreads();   // sw/sbase reads done before next pass overwrites
    }
}

// ---------------------------------------------------------------------------
// Both scatters in one launch: blocks 0..63 points, 64..319 queries.
// ---------------------------------------------------------------------------
__global__ __launch_bounds__(256)
void scatter_kernel(const float4* __restrict__ paug, const float* __restrict__ p1,
                    int* __restrict__ cursors_p, int* __restrict__ cursors_q,
                    float4* __restrict__ sortedP, unsigned short* __restrict__ sIdx,
                    unsigned short* __restrict__ qlist)
{
    if (blockIdx.x < 64) {
        const int i = blockIdx.x * 256 + threadIdx.x;   // over N2R
        const float4 v = paug[i];
        const int b = i >> 12;
        const int cell = cell_of(v.x, v.y, v.z);
        const int pos = atomicAdd(&cursors_p[b * NCELL + cell], 1);
        sortedP[(size_t)b * NPB + pos] = v;
        sIdx[(size_t)b * NPB + pos] = (unsigned short)(i & 4095);
    } else {
        const int i = (blockIdx.x - 64) * 256 + threadIdx.x;   // over N1R
        const float x = p1[(size_t)i * 3 + 0];
        const float y = p1[(size_t)i * 3 + 1];
        const float z = p1[(size_t)i * 3 + 2];
        const int b = i >> 14;
        const int cell = cell_of(x, y, z);
        const int pos = atomicAdd(&cursors_q[b * NCELL + cell], 1);
        qlist[(size_t)b * NQB + pos] = (unsigned short)(i & 16383);
    }
}

// ---------------------------------------------------------------------------
// GEMM body (device template): BM x 128 tile, 4 waves, 1-barrier ping-pong
// dbuf, reg-staged cvt path; per-thread code identical to the proven r6
// structure -> Y bitwise identical.  Non-atomic stat partials
// (row = bx*2 + wave_m, disjoint cols per y-block/wave; r5 lesson).
// ---------------------------------------------------------------------------
template<int BM>
static __device__ __forceinline__ void gemm_body(
    int bx, int by,
    const float* __restrict__ X, const short* __restrict__ WT,
    const float* __restrict__ bias, float* __restrict__ Y,
    float* __restrict__ partS, float* __restrict__ partQ,
    int Kdim, short* __restrict__ As0, short* __restrict__ As1)
{
    constexpr int MI  = BM / 32;     // m-frags per wave (4 or 2)
    constexpr int NPF = BM / 32;     // v4f prefetch regs per thread (4 or 2)
    constexpr int TPR = 256 / BM;    // threads per row (2 or 4)
    constexpr int FPT = BM / 8;      // floats staged per thread (16 or 8)

    const int bm0 = bx * BM;
    const int bn0 = by * 128;
    const int wave = threadIdx.x >> 6;
    const int lane = threadIdx.x & 63;
    const int wm0 = (wave >> 1) * (BM / 2);
    const int wn0 = (wave & 1) * 64;
    const int col = lane & 15, quad = lane >> 4;

    const int srow = threadIdx.x / TPR;
    const int skh  = (threadIdx.x % TPR) * FPT;
    const float* sbase = X + (size_t)(bm0 + srow) * Kdim + skh;
    short* sdst0 = As0 + srow * ASTRIDE + skh;
    short* sdst1 = As1 + srow * ASTRIDE + skh;

    v4f acc[MI][4];
#pragma unroll
    for (int i = 0; i < MI; ++i)
#pragma unroll
        for (int j = 0; j < 4; ++j) acc[i][j] = (v4f){0.f, 0.f, 0.f, 0.f};

    const short* wbase = WT + (size_t)(bn0 + wn0 + col) * Kdim + quad * 8;

    // prologue: chunk0 -> regs -> buf0; chunk1 -> regs
    v4f pf[NPF];
#pragma unroll
    for (int i = 0; i < NPF; ++i) pf[i] = *(const v4f*)(sbase + i * 4);
    {
        v8s wv;
#pragma unroll
        for (int j = 0; j < NPF / 2; ++j) {
#pragma unroll
            for (int t = 0; t < 4; ++t) {
                wv[t]     = f2bs(pf[2 * j][t]);
                wv[t + 4] = f2bs(pf[2 * j + 1][t]);
            }
            *(v8s*)(sdst0 + j * 8) = wv;
        }
    }
    if (32 < Kdim)
#pragma unroll
        for (int i = 0; i < NPF; ++i) pf[i] = *(const v4f*)(sbase + 32 + i * 4);

    const int NC = Kdim >> 5;
    for (int c = 0; c < NC; ++c) {
        const int k0 = c << 5;
        const bool more = (c + 1 < NC);

        // cvt next chunk (waits on its global loads) before the barrier
        v8s wv[NPF / 2];
        if (more) {
#pragma unroll
            for (int j = 0; j < NPF / 2; ++j)
#pragma unroll
                for (int t = 0; t < 4; ++t) {
                    wv[j][t]     = f2bs(pf[2 * j][t]);
                    wv[j][t + 4] = f2bs(pf[2 * j + 1][t]);
                }
        }
        __syncthreads();   // buf[c&1] writes visible; prior reads of buf[(c+1)&1] done
        if (more) {
            short* sd = (c & 1) ? sdst0 : sdst1;     // buf[(c+1)&1]
#pragma unroll
            for (int j = 0; j < NPF / 2; ++j) *(v8s*)(sd + j * 8) = wv[j];
        }

        // B fragments for this chunk
        v8s bf[4];
#pragma unroll
        for (int ni = 0; ni < 4; ++ni)
            bf[ni] = *(const v8s*)(wbase + (size_t)(ni * 16) * Kdim + k0);

        // global prefetch of chunk c+2 (in flight through MFMA)
        if (c + 2 < NC) {
            const float* np = sbase + k0 + 64;
#pragma unroll
            for (int i = 0; i < NPF; ++i) pf[i] = *(const v4f*)(np + i * 4);
        }

        const short* bufc = (c & 1) ? As1 : As0;
        v8s a[MI];
#pragma unroll
        for (int mi = 0; mi < MI; ++mi)
            a[mi] = *(const v8s*)(bufc + (wm0 + mi * 16 + col) * ASTRIDE + quad * 8);
#pragma unroll
        for (int mi = 0; mi < MI; ++mi)
#pragma unroll
            for (int ni = 0; ni < 4; ++ni)
                acc[mi][ni] = __builtin_amdgcn_mfma_f32_16x16x32_bf16(a[mi], bf[ni], acc[mi][ni], 0, 0, 0);
    }

    // epilogue: bias + store + non-atomic partial stats
    float* pS = partS + (size_t)(bx * 2 + (wave >> 1)) * CC;
    float* pQ = partQ + (size_t)(bx * 2 + (wave >> 1)) * CC;
#pragma unroll
    for (int ni = 0; ni < 4; ++ni) {
        const int n = bn0 + wn0 + ni * 16 + col;
        const float bv = bias[n];
        float s = 0.f, q = 0.f;
#pragma unroll
        for (int mi = 0; mi < MI; ++mi) {
            const int m = bm0 + wm0 + mi * 16 + quad * 4;
#pragma unroll
            for (int r = 0; r < 4; ++r) {
                const float y = acc[mi][ni][r] + bv;
                Y[(size_t)(m + r) * CC + n] = y;
                s += y; q += y * y;
            }
        }
        s += __shfl_xor(s, 16); q += __shfl_xor(q, 16);
        s += __shfl_xor(s, 32); q += __shfl_xor(q, 32);
        if (quad == 0) { pS[n] = s; pQ[n] = q; }
    }
}

// ---------------------------------------------------------------------------
// BOTH GEMMs in one dispatch, both BM=64 (occupancy experiment: 2560 small
// blocks, 10 KB LDS, ~64 VGPR -> many more co-resident blocks/CU than the
// r8 shape whose Occupancy was 27% with ~30us-serialized 4-wave blocks).
// blocks 0..2047: gemm1 (KD=256); 2048..2559: gemm2 (KD=512).
// ---------------------------------------------------------------------------
__global__ __launch_bounds__(256)
void gemm_both_kernel(const float* __restrict__ feat1, const short* __restrict__ WT1,
                      const float* __restrict__ b1, float* __restrict__ Y1,
                      float* __restrict__ pS1, float* __restrict__ pQ1,
                      const float* __restrict__ feat2, const short* __restrict__ WT2,
                      const float* __restrict__ b2, float* __restrict__ Y2,
                      float* __restrict__ pS2, float* __restrict__ pQ2)
{
    __shared__ short As[2][64 * ASTRIDE];    // 10 KB
    const int id = blockIdx.x;
    if (id < 2048) {
        gemm_body<64>(id >> 1, id & 1, feat1, WT1, b1, Y1, pS1, pQ1, 256,
                      As[0], As[1]);
    } else {
        const int j = id - 2048;
        gemm_body<64>(j >> 1, j & 1, feat2, WT2, b2, Y2, pS2, pQ2, 512,
                      As[0], As[1]);
    }
}

// ---------------------------------------------------------------------------
// Partial-stat reduce: blocks 0..31 sum BN1's 2048 partial rows (64 each),
// blocks 32..39 sum BN2's 512 rows (64 each); ~32/8 atomics per address.
// ---------------------------------------------------------------------------
__global__ __launch_bounds__(256)
void stat_reduce_kernel(const float* __restrict__ pS1, const float* __restrict__ pQ1,
                        const float* __restrict__ pS2, const float* __restrict__ pQ2,
                        float* __restrict__ stats)
{
    const int c = threadIdx.x;
    const bool two = blockIdx.x >= 32;
    const float* pS = two ? pS2 : pS1;
    const float* pQ = two ? pQ2 : pQ1;
    const int r0 = (two ? (blockIdx.x - 32) : blockIdx.x) * 64;
    float s = 0.f, q = 0.f;
    for (int r = r0; r < r0 + 64; ++r) {
        s += pS[(size_t)r * CC + c];
        q += pQ[(size_t)r * CC + c];
    }
    float* st = stats + (two ? 512 : 0);
    atomicAdd(&st[c], s);
    atomicAdd(&st[256 + c], q);
}

// ---------------------------------------------------------------------------
// Finalize BN constants: a = g*rsqrt(var+eps), c = beta - a*mu
// ---------------------------------------------------------------------------
__global__ __launch_bounds__(512)
void finalize_kernel(const float* __restrict__ sums,
                     const float* __restrict__ g1, const float* __restrict__ be1,
                     const float* __restrict__ g2, const float* __restrict__ be2,
                     float* __restrict__ ac)
{
    const int t = threadIdx.x;           // 0..511
    const int c = t & 255;
    const int which = t >> 8;            // 0: BN1, 1: BN2
    const float* s = sums + which * 512;
    const double n = which ? (double)N2R : (double)N1R;
    const double mu = (double)s[c] / n;
    const double var = (double)s[c + 256] / n - mu * mu;
    const float g  = which ? g2[c]  : g1[c];
    const float be = which ? be2[c] : be1[c];
    const double a  = (double)g / sqrt(var + 1e-5);
    const double cv = (double)be - a * mu;
    ac[which * 512 + c]       = (float)a;
    ac[which * 512 + 256 + c] = (float)cv;
}

// ---------------------------------------------------------------------------
// Grid KNN: cell-sorted queries scan their 27-cell neighborhood against the
// batch's cell-sorted points staged in LDS.  Exact fp32 distances
// (bit-matching the reference); lexicographic (d, idx) top-3.  Coverage:
// every point within 0.125 of q lies inside the clamped 27-cell block, so
// b2 < 0.125^2 certifies exactness; else idx[0] = -1 sentinel and the
// final kernel brute-forces that row inline (no separate bf launch).
// Block: 256 thr = 128 queries x 2 half-scans (cells 0..13 / 14..26).
// ---------------------------------------------------------------------------
__global__ __launch_bounds__(256)
void knn_grid_kernel(const float* __restrict__ p1,
                     const float4* __restrict__ sortedP,
                     const unsigned short* __restrict__ sIdx16,
                     const int* __restrict__ starts_p,
                     const unsigned short* __restrict__ qlist,
                     int* __restrict__ idx_out, float* __restrict__ w_out)
{
#pragma clang fp contract(off)
    __shared__ float4 sP[NPB];                 // 64 KB
    __shared__ unsigned short sI[NPB];         // 8 KB
    __shared__ int sS[513];                    // 2 KB
    __shared__ float mD[128 * 3];              // 1.5 KB
    __shared__ int   mI[128 * 3];              // 1.5 KB

    const int b = blockIdx.x >> 7;             // 128 blocks per batch
    const int slot0 = (blockIdx.x & 127) * 128;
    const int tid = threadIdx.x;
    const int lq = tid & 127;                  // query slot within block
    const int half = tid >> 7;

    // stage the batch's cell-sorted points + idx + starts
    {
        const float4* gp = sortedP + (size_t)b * NPB;
        for (int i = tid; i < NPB; i += 256) sP[i] = gp[i];
        const unsigned int* gi = (const unsigned int*)(sIdx16 + (size_t)b * NPB);
        unsigned int* li = (unsigned int*)sI;
        for (int i = tid; i < NPB / 2; i += 256) li[i] = gi[i];
        const int* gs = starts_p + b * 513;
        for (int i = tid; i < 513; i += 256) sS[i] = gs[i];
    }

    const int q = qlist[(size_t)b * NQB + slot0 + lq];   // batch-local query id
    const int qid = b * NQB + q;
    const float qx = p1[(size_t)qid * 3 + 0];
    const float qy = p1[(size_t)qid * 3 + 1];
    const float qz = p1[(size_t)qid * 3 + 2];
    const float qq = (qx * qx + qy * qy) + qz * qz;
    const int cqx = min(7, (int)(qx * 8.0f));
    const int cqy = min(7, (int)(qy * 8.0f));
    const int cqz = min(7, (int)(qz * 8.0f));

    __syncthreads();

    float b0 = 3.0e38f, b1 = 3.0e38f, b2 = 3.0e38f;
    int i0 = 0x7fffffff, i1 = 0x7fffffff, i2 = 0x7fffffff;

    int n = 0;
    for (int dz = -1; dz <= 1; ++dz)
        for (int dy = -1; dy <= 1; ++dy)
            for (int dx = -1; dx <= 1; ++dx, ++n) {
                if (half ? (n < 14) : (n >= 14)) continue;   // 14 / 13 cell split
                const int cz = cqz + dz, cy = cqy + dy, cx = cqx + dx;
                if (((unsigned)cz | (unsigned)cy | (unsigned)cx) > 7u) continue;
                const int cell = (cz << 6) | (cy << 3) | cx;
                const int ks = sS[cell], ke = sS[cell + 1];
                for (int k = ks; k < ke; ++k) {
                    const float4 P = sP[k];
                    const int si = sI[k];
                    const float dot = fmaf(qz, P.z, fmaf(qy, P.y, qx * P.x));
                    const float d = fmaf(-2.0f, dot, qq + P.w);
                    ins3(d, si, b0, b1, b2, i0, i1, i2);
                }
            }

    if (half) {
        mD[lq * 3 + 0] = b0; mD[lq * 3 + 1] = b1; mD[lq * 3 + 2] = b2;
        mI[lq * 3 + 0] = i0; mI[lq * 3 + 1] = i1; mI[lq * 3 + 2] = i2;
    }
    __syncthreads();
    if (!half) {
#pragma unroll
        for (int r = 0; r < 3; ++r)
            ins3(mD[lq * 3 + r], mI[lq * 3 + r], b0, b1, b2, i0, i1, i2);

        if (!(b2 < GRID_FAIL_R2)) i0 = -1;     // sentinel: final brute-forces

        const float r0 = 1.0f / (fmaxf(b0, 0.0f) + 1e-8f);
        const float r1 = 1.0f / (fmaxf(b1, 0.0f) + 1e-8f);
        const float r2 = 1.0f / (fmaxf(b2, 0.0f) + 1e-8f);
        const float rs = (r0 + r1) + r2;
        idx_out[(size_t)qid * 3 + 0] = i0;
        idx_out[(size_t)qid * 3 + 1] = i1;
        idx_out[(size_t)qid * 3 + 2] = i2;
        w_out[(size_t)qid * 3 + 0] = r0 / rs;
        w_out[(size_t)qid * 3 + 1] = r1 / rs;
        w_out[(size_t)qid * 3 + 2] = r2 / rs;
    }
}

// ---------------------------------------------------------------------------
// Final: out[r][c] = relu(a1*Y1+c1) + sum_k w_k * relu(a2*Y2[idx_k]+c2).
// Rows in qlist (cell-sorted) order for gather locality.  Rows flagged with
// idx[0] == -1 (~0.5%, grid-KNN boundary failures) are brute-forced inline
// by their wave (same ins3+butterfly as the old knn_bf kernel).
// ---------------------------------------------------------------------------
__global__ __launch_bounds__(256)
void final_kernel(float* __restrict__ Y1out,
                  const float* __restrict__ Y2raw,
                  const float* __restrict__ ac,        // a1,c1,a2,c2 (256 each)
                  const int* __restrict__ idx, const float* __restrict__ w,
                  const unsigned short* __restrict__ qlist,
                  const float* __restrict__ p1, const float4* __restrict__ paug)
{
#pragma clang fp contract(off)
    const int slot = blockIdx.x * 4 + (threadIdx.x >> 6);
    const int b = slot >> 14;
    const int r = b * NQB + qlist[slot];     // cell-sorted row
    const int cg = threadIdx.x & 63;

    const int* ir = idx + (size_t)r * 3;
    int i0 = ir[0], i1 = ir[1], i2 = ir[2];
    float w0, w1, w2;
    if (i0 >= 0) {
        const float* wr = w + (size_t)r * 3;
        w0 = wr[0]; w1 = wr[1]; w2 = wr[2];
    } else {
        // wave-uniform brute force over the batch's 4096 points
        const float qx = p1[(size_t)r * 3 + 0];
        const float qy = p1[(size_t)r * 3 + 1];
        const float qz = p1[(size_t)r * 3 + 2];
        const float qq = (qx * qx + qy * qy) + qz * qz;
        float b0 = 3.0e38f, b1 = 3.0e38f, b2 = 3.0e38f;
        i0 = 0x7fffffff; i1 = 0x7fffffff; i2 = 0x7fffffff;
        const float4* pb = paug + (size_t)b * NPB;
        for (int j = cg; j < NPB; j += 64) {
            const float4 P = pb[j];
            const float dot = fmaf(qz, P.z, fmaf(qy, P.y, qx * P.x));
            const float d = fmaf(-2.0f, dot, qq + P.w);
            ins3(d, j, b0, b1, b2, i0, i1, i2);
        }
        for (int m = 1; m < 64; m <<= 1) {
            const float c0 = __shfl_xor(b0, m), c1 = __shfl_xor(b1, m), c2 = __shfl_xor(b2, m);
            const int j0 = __shfl_xor(i0, m), j1 = __shfl_xor(i1, m), j2 = __shfl_xor(i2, m);
            ins3(c0, j0, b0, b1, b2, i0, i1, i2);
            ins3(c1, j1, b0, b1, b2, i0, i1, i2);
            ins3(c2, j2, b0, b1, b2, i0, i1, i2);
        }
        const float r0 = 1.0f / (fmaxf(b0, 0.0f) + 1e-8f);
        const float r1 = 1.0f / (fmaxf(b1, 0.0f) + 1e-8f);
        const float r2 = 1.0f / (fmaxf(b2, 0.0f) + 1e-8f);
        const float rs = (r0 + r1) + r2;
        w0 = r0 / rs; w1 = r1 / rs; w2 = r2 / rs;
    }

    v4f a1 = *(const v4f*)(ac + cg * 4);
    v4f c1 = *(const v4f*)(ac + 256 + cg * 4);
    v4f a2 = *(const v4f*)(ac + 512 + cg * 4);
    v4f c2 = *(const v4f*)(ac + 768 + cg * 4);
    v4f y = *(const v4f*)(Y1out + (size_t)r * CC + cg * 4);
    v4f s;
#pragma unroll
    for (int j = 0; j < 4; ++j)
        s[j] = fmaxf(fmaf(a1[j], y[j], c1[j]), 0.f);

    const int   id3[3] = { i0, i1, i2 };
    const float wk3[3] = { w0, w1, w2 };
#pragma unroll
    for (int k = 0; k < 3; ++k) {
        const float wk = wk3[k];
        v4f g = *(const v4f*)(Y2raw + ((size_t)(b * NPB + id3[k])) * CC + cg * 4);
#pragma unroll
        for (int j = 0; j < 4; ++j) {
            const float gv = fmaxf(fmaf(a2[j], g[j], c2[j]), 0.f);   // == bnrelu
            s[j] = fmaf(wk, gv, s[j]);
        }
    }
    *(v4f*)(Y1out + (size_t)r * CC + cg * 4) = s;
}

// ---------------------------------------------------------------------------
extern "C" void kernel_launch(void* const* d_in, const int* in_sizes, int n_in,
                              void* d_out, int out_size, void* d_ws, size_t ws_size,
                              hipStream_t stream)
{
    const float* point1 = (const float*)d_in[0];
    const float* feat1  = (const float*)d_in[1];
    const float* point2 = (const float*)d_in[2];
    const float* feat2  = (const float*)d_in[3];
    const float* W1     = (const float*)d_in[4];
    const float* b1     = (const float*)d_in[5];
    const float* g1     = (const float*)d_in[6];
    const float* beta1  = (const float*)d_in[7];
    const float* W2     = (const float*)d_in[8];
    const float* b2     = (const float*)d_in[9];
    const float* g2     = (const float*)d_in[10];
    const float* beta2  = (const float*)d_in[11];

    float* Y1 = (float*)d_out;                            // 64 MB (reused as output)

    char* ws = (char*)d_ws;
    float*          Y2       = (float*)ws;                                   // 16 MB (raw, BN fused in final)
    float*          stats    = (float*)(ws + (size_t)16777216);              // 4 KB
    int*            counts_p = (int*)  (ws + (size_t)16781312);              // 8 KB
    int*            counts_q = (int*)  (ws + (size_t)16789504);              // 8 KB
    int*            cursors_p= (int*)  (ws + (size_t)16801792);              // 8 KB
    int*            cursors_q= (int*)  (ws + (size_t)16809984);              // 8 KB
    int*            starts_p = (int*)  (ws + (size_t)16818176);              // 8.2 KB
    float*          ac       = (float*)(ws + (size_t)16826624);              // 4 KB
    unsigned short* sIdx16   = (unsigned short*)(ws + (size_t)16830720);     // 32 KB
    unsigned short* qlist    = (unsigned short*)(ws + (size_t)16863488);     // 128 KB
    float4*         sortedP  = (float4*)(ws + (size_t)17256704);             // 256 KB
    int*            idxb     = (int*)  (ws + (size_t)17518848);              // 768 KB
    float*          wb       = (float*)(ws + (size_t)18305280);              // 768 KB
    short*          WT1      = (short*)(ws + (size_t)19091712);              // 128 KB
    short*          WT2      = (short*)(ws + (size_t)19222784);              // 256 KB
    float4*         paug     = (float4*)(ws + (size_t)19484928);             // 256 KB
    float*          partS1   = (float*)(ws + (size_t)19747072);              // 2 MB (2048 x 256)
    float*          partQ1   = (float*)(ws + (size_t)21844224);              // 2 MB
    float*          partS2   = (float*)(ws + (size_t)23941376);              // 512 KB (512 x 256)
    float*          partQ2   = (float*)(ws + (size_t)24465664);              // 512 KB

    // zero: stats (4KB) + counts_p (8KB) + counts_q (8KB) (+pad)
    hipMemsetAsync(stats, 0, 24576, stream);

    // Merged prep: W transposes + paug + histograms; prefix; scatters
    prep_kernel<<<1088, 256, 0, stream>>>(W1, W2, WT1, WT2, point2, point1,
                                          paug, counts_p, counts_q);
    prefix_kernel<<<1, 512, 0, stream>>>(counts_p, cursors_p, starts_p, counts_q, cursors_q);
    scatter_kernel<<<320, 256, 0, stream>>>(paug, point1, cursors_p, cursors_q,
                                            sortedP, sIdx16, qlist);

    // Both GEMMs, one dispatch, BM=64 (2048 blocks gemm1 + 512 blocks gemm2)
    gemm_both_kernel<<<2560, 256, 0, stream>>>(feat1, WT1, b1, Y1, partS1, partQ1,
                                               feat2, WT2, b2, Y2, partS2, partQ2);

    // Partial reduce (32 blocks BN1 + 8 blocks BN2) then finalize
    stat_reduce_kernel<<<40, 256, 0, stream>>>(partS1, partQ1, partS2, partQ2, stats);
    finalize_kernel<<<1, 512, 0, stream>>>(stats, g1, beta1, g2, beta2, ac);

    // Grid KNN (exact; boundary failures flagged with idx[0] = -1)
    knn_grid_kernel<<<512, 256, 0, stream>>>(point1, sortedP, sIdx16, starts_p,
                                             qlist, idxb, wb);

    // out = relu(bn(Y1)) + weighted gather of relu(bn(Y2)), cell-sorted order;
    // flagged rows brute-forced inline
    final_kernel<<<N1R / 4, 256, 0, stream>>>(Y1, Y2, ac, idxb, wb, qlist,
                                              point1, paug);
}

// Round 10
// 303.047 us; speedup vs baseline: 1.0427x; 1.0427x over previous
//
#include <hip/hip_runtime.h>
#include <hip/hip_bf16.h>
#include <math.h>

// Problem constants
#define N1R 65536   // B*N1 query rows
#define N2R 16384   // B*N2 point rows
#define NPB 4096    // N2 per batch
#define NQB 16384   // N1 per batch
#define CC  256     // COUT
#define ASTRIDE 40  // LDS A-tile row stride in bf16 elems (80B: 16B-aligned, ~2-way banks)
#define NCELL 512   // 8x8x8 grid cells per batch
#define GRID_FAIL_R2 0.015625f   // (1/8)^2 coverage bound of the 27-cell block

typedef __attribute__((ext_vector_type(4))) float v4f;
typedef __attribute__((ext_vector_type(8))) short v8s;

static __device__ __forceinline__ short f2bs(float f) {
    union { __hip_bfloat16 h; short s; } u;
    u.h = __float2bfloat16(f);
    return u.s;
}

static __device__ __forceinline__ int cell_of(float x, float y, float z) {
    const int cx = min(7, (int)(x * 8.0f));
    const int cy = min(7, (int)(y * 8.0f));
    const int cz = min(7, (int)(z * 8.0f));
    return (cz << 6) | (cy << 3) | cx;
}

// branchless lexicographic (d, idx) top-3 insert; keeps b0<=b1<=b2 sorted
static __device__ __forceinline__ void ins3(float d, int si,
    float& b0, float& b1, float& b2, int& i0, int& i1, int& i2)
{
    const bool lt0 = (d < b0) | ((d == b0) & (si < i0));
    const bool lt1 = (d < b1) | ((d == b1) & (si < i1));
    const bool lt2 = (d < b2) | ((d == b2) & (si < i2));
    b2 = lt1 ? b1 : (lt2 ? d : b2);   i2 = lt1 ? i1 : (lt2 ? si : i2);
    b1 = lt0 ? b0 : (lt1 ? d : b1);   i1 = lt0 ? i0 : (lt1 ? si : i1);
    b0 = lt0 ? d  : b0;               i0 = lt0 ? si : i0;
}

// ---------------------------------------------------------------------------
// Merged prep: W transposes + paug + both cell histograms in ONE launch.
// ---------------------------------------------------------------------------
__global__ __launch_bounds__(256)
void prep_kernel(const float* __restrict__ W1f, const float* __restrict__ W2f,
                 short* __restrict__ WT1, short* __restrict__ WT2,
                 const float* __restrict__ p2, const float* __restrict__ p1,
                 float4* __restrict__ paug,
                 int* __restrict__ counts_p, int* __restrict__ counts_q)
{
#pragma clang fp contract(off)
    const int bid = blockIdx.x;
    if (bid < 768) {
        const int i = bid * 256 + threadIdx.x;   // 0 .. 196607
        if (i < 65536) {
            const int k = i >> 8, n = i & 255;
            WT1[(size_t)n * 256 + k] = f2bs(W1f[i]);
        } else {
            const int j = i - 65536;
            const int k = j >> 8, n = j & 255;
            WT2[(size_t)n * 512 + k] = f2bs(W2f[j]);
        }
    } else if (bid < 832) {
        const int i = (bid - 768) * 256 + threadIdx.x;   // over N2R
        const float x = p2[(size_t)i * 3 + 0];
        const float y = p2[(size_t)i * 3 + 1];
        const float z = p2[(size_t)i * 3 + 2];
        float4 v;
        v.x = x; v.y = y; v.z = z;
        v.w = (x * x + y * y) + z * z;
        paug[i] = v;
        const int b = i >> 12;
        atomicAdd(&counts_p[b * NCELL + cell_of(x, y, z)], 1);
    } else {
        const int i = (bid - 832) * 256 + threadIdx.x;   // over N1R
        const float x = p1[(size_t)i * 3 + 0];
        const float y = p1[(size_t)i * 3 + 1];
        const float z = p1[(size_t)i * 3 + 2];
        const int b = i >> 14;
        atomicAdd(&counts_q[b * NCELL + cell_of(x, y, z)], 1);
    }
}

// ---------------------------------------------------------------------------
// Exclusive prefix over 512 cells, 4 batches x {points, queries}.
// Wave-shuffle Hillis-Steele scan: 3 syncthreads/pass.
// ---------------------------------------------------------------------------
__global__ __launch_bounds__(512)
void prefix_kernel(const int* __restrict__ counts_p, int* __restrict__ cursors_p,
                   int* __restrict__ starts_p,
                   const int* __restrict__ counts_q, int* __restrict__ cursors_q)
{
    __shared__ int sw[8];      // per-wave totals
    __shared__ int sbase[8];   // per-wave exclusive bases
    const int t = threadIdx.x;
    const int lane = t & 63, wid = t >> 6;
    for (int a = 0; a < 8; ++a) {
        const int b = a & 3;
        const int* cnt = (a < 4) ? counts_p + b * NCELL : counts_q + b * NCELL;
        const int v = cnt[t];
        int incl = v;
#pragma unroll
        for (int off = 1; off < 64; off <<= 1) {
            const int u = __shfl_up(incl, off);
            incl += (lane >= off) ? u : 0;
        }
        if (lane == 63) sw[wid] = incl;
        __syncthreads();
        if (t == 0) {
            int s = 0;
#pragma unroll
            for (int w = 0; w < 8; ++w) { const int x = sw[w]; sbase[w] = s; s += x; }
        }
        __syncthreads();
        const int inclT = incl + sbase[wid];
        const int excl = inclT - v;
        if (a < 4) {
            starts_p[b * 513 + t] = excl;
            if (t == 511) starts_p[b * 513 + 512] = inclT;   // == 4096
            cursors_p[b * NCELL + t] = excl;
        } else {
            cursors_q[b * NCELL + t] = excl;
        }
        __syncthreads();   // sw/sbase reads done before next pass overwrites
    }
}

// ---------------------------------------------------------------------------
// Both scatters in one launch: blocks 0..63 points, 64..319 queries.
// ---------------------------------------------------------------------------
__global__ __launch_bounds__(256)
void scatter_kernel(const float4* __restrict__ paug, const float* __restrict__ p1,
                    int* __restrict__ cursors_p, int* __restrict__ cursors_q,
                    float4* __restrict__ sortedP, unsigned short* __restrict__ sIdx,
                    unsigned short* __restrict__ qlist)
{
    if (blockIdx.x < 64) {
        const int i = blockIdx.x * 256 + threadIdx.x;   // over N2R
        const float4 v = paug[i];
        const int b = i >> 12;
        const int cell = cell_of(v.x, v.y, v.z);
        const int pos = atomicAdd(&cursors_p[b * NCELL + cell], 1);
        sortedP[(size_t)b * NPB + pos] = v;
        sIdx[(size_t)b * NPB + pos] = (unsigned short)(i & 4095);
    } else {
        const int i = (blockIdx.x - 64) * 256 + threadIdx.x;   // over N1R
        const float x = p1[(size_t)i * 3 + 0];
        const float y = p1[(size_t)i * 3 + 1];
        const float z = p1[(size_t)i * 3 + 2];
        const int b = i >> 14;
        const int cell = cell_of(x, y, z);
        const int pos = atomicAdd(&cursors_q[b * NCELL + cell], 1);
        qlist[(size_t)b * NQB + pos] = (unsigned short)(i & 16383);
    }
}

// ---------------------------------------------------------------------------
// GEMM body (device template): BM x 128 tile, 4 waves, 1-barrier ping-pong
// dbuf, reg-staged cvt path (r8-proven; Y bitwise stable).  Non-atomic stat
// partials (row = bx*2 + wave_m; disjoint cols per y-block/wave; r5 lesson).
// ---------------------------------------------------------------------------
template<int BM>
static __device__ __forceinline__ void gemm_body(
    int bx, int by,
    const float* __restrict__ X, const short* __restrict__ WT,
    const float* __restrict__ bias, float* __restrict__ Y,
    float* __restrict__ partS, float* __restrict__ partQ,
    int Kdim, short* __restrict__ As0, short* __restrict__ As1)
{
    constexpr int MI  = BM / 32;     // m-frags per wave (4 or 2)
    constexpr int NPF = BM / 32;     // v4f prefetch regs per thread (4 or 2)
    constexpr int TPR = 256 / BM;    // threads per row (2 or 4)
    constexpr int FPT = BM / 8;      // floats staged per thread (16 or 8)

    const int bm0 = bx * BM;
    const int bn0 = by * 128;
    const int wave = threadIdx.x >> 6;
    const int lane = threadIdx.x & 63;
    const int wm0 = (wave >> 1) * (BM / 2);
    const int wn0 = (wave & 1) * 64;
    const int col = lane & 15, quad = lane >> 4;

    const int srow = threadIdx.x / TPR;
    const int skh  = (threadIdx.x % TPR) * FPT;
    const float* sbase = X + (size_t)(bm0 + srow) * Kdim + skh;
    short* sdst0 = As0 + srow * ASTRIDE + skh;
    short* sdst1 = As1 + srow * ASTRIDE + skh;

    v4f acc[MI][4];
#pragma unroll
    for (int i = 0; i < MI; ++i)
#pragma unroll
        for (int j = 0; j < 4; ++j) acc[i][j] = (v4f){0.f, 0.f, 0.f, 0.f};

    const short* wbase = WT + (size_t)(bn0 + wn0 + col) * Kdim + quad * 8;

    // prologue: chunk0 -> regs -> buf0; chunk1 -> regs
    v4f pf[NPF];
#pragma unroll
    for (int i = 0; i < NPF; ++i) pf[i] = *(const v4f*)(sbase + i * 4);
    {
        v8s wv;
#pragma unroll
        for (int j = 0; j < NPF / 2; ++j) {
#pragma unroll
            for (int t = 0; t < 4; ++t) {
                wv[t]     = f2bs(pf[2 * j][t]);
                wv[t + 4] = f2bs(pf[2 * j + 1][t]);
            }
            *(v8s*)(sdst0 + j * 8) = wv;
        }
    }
    if (32 < Kdim)
#pragma unroll
        for (int i = 0; i < NPF; ++i) pf[i] = *(const v4f*)(sbase + 32 + i * 4);

    const int NC = Kdim >> 5;
    for (int c = 0; c < NC; ++c) {
        const int k0 = c << 5;
        const bool more = (c + 1 < NC);

        // cvt next chunk (waits on its global loads) before the barrier
        v8s wv[NPF / 2];
        if (more) {
#pragma unroll
            for (int j = 0; j < NPF / 2; ++j)
#pragma unroll
                for (int t = 0; t < 4; ++t) {
                    wv[j][t]     = f2bs(pf[2 * j][t]);
                    wv[j][t + 4] = f2bs(pf[2 * j + 1][t]);
                }
        }
        __syncthreads();   // buf[c&1] writes visible; prior reads of buf[(c+1)&1] done
        if (more) {
            short* sd = (c & 1) ? sdst0 : sdst1;     // buf[(c+1)&1]
#pragma unroll
            for (int j = 0; j < NPF / 2; ++j) *(v8s*)(sd + j * 8) = wv[j];
        }

        // B fragments for this chunk
        v8s bf[4];
#pragma unroll
        for (int ni = 0; ni < 4; ++ni)
            bf[ni] = *(const v8s*)(wbase + (size_t)(ni * 16) * Kdim + k0);

        // global prefetch of chunk c+2 (in flight through MFMA)
        if (c + 2 < NC) {
            const float* np = sbase + k0 + 64;
#pragma unroll
            for (int i = 0; i < NPF; ++i) pf[i] = *(const v4f*)(np + i * 4);
        }

        const short* bufc = (c & 1) ? As1 : As0;
        v8s a[MI];
#pragma unroll
        for (int mi = 0; mi < MI; ++mi)
            a[mi] = *(const v8s*)(bufc + (wm0 + mi * 16 + col) * ASTRIDE + quad * 8);
#pragma unroll
        for (int mi = 0; mi < MI; ++mi)
#pragma unroll
            for (int ni = 0; ni < 4; ++ni)
                acc[mi][ni] = __builtin_amdgcn_mfma_f32_16x16x32_bf16(a[mi], bf[ni], acc[mi][ni], 0, 0, 0);
    }

    // epilogue: bias + store + non-atomic partial stats
    float* pS = partS + (size_t)(bx * 2 + (wave >> 1)) * CC;
    float* pQ = partQ + (size_t)(bx * 2 + (wave >> 1)) * CC;
#pragma unroll
    for (int ni = 0; ni < 4; ++ni) {
        const int n = bn0 + wn0 + ni * 16 + col;
        const float bv = bias[n];
        float s = 0.f, q = 0.f;
#pragma unroll
        for (int mi = 0; mi < MI; ++mi) {
            const int m = bm0 + wm0 + mi * 16 + quad * 4;
#pragma unroll
            for (int r = 0; r < 4; ++r) {
                const float y = acc[mi][ni][r] + bv;
                Y[(size_t)(m + r) * CC + n] = y;
                s += y; q += y * y;
            }
        }
        s += __shfl_xor(s, 16); q += __shfl_xor(q, 16);
        s += __shfl_xor(s, 32); q += __shfl_xor(q, 32);
        if (quad == 0) { pS[n] = s; pQ[n] = q; }
    }
}

// ---------------------------------------------------------------------------
// KNN body, UNSTAGED: reads cell-sorted points/idx/starts straight from
// global (sortedP = 256 KB/batch, L2-resident; cell-sorted adjacent lanes
// read the same addresses -> broadcast).  LDS use: only the 3 KB merge
// buffers, carved from the caller's scratch.  Exact distances, lex (d,idx)
// top-3; boundary failures flagged idx[0] = -1 (final brute-forces inline).
// ---------------------------------------------------------------------------
static __device__ __forceinline__ void knn_body(
    int bid,
    const float* __restrict__ p1, const float4* __restrict__ sortedP,
    const unsigned short* __restrict__ sIdx16, const int* __restrict__ starts_p,
    const unsigned short* __restrict__ qlist,
    int* __restrict__ idx_out, float* __restrict__ w_out,
    float* __restrict__ mD, int* __restrict__ mI)
{
#pragma clang fp contract(off)
    const int b = bid >> 7;                    // 128 blocks per batch
    const int slot0 = (bid & 127) * 128;
    const int tid = threadIdx.x;
    const int lq = tid & 127;                  // query slot within block
    const int half = tid >> 7;

    const float4* pb = sortedP + (size_t)b * NPB;
    const unsigned short* ib = sIdx16 + (size_t)b * NPB;
    const int* st = starts_p + b * 513;

    const int q = qlist[(size_t)b * NQB + slot0 + lq];   // batch-local query id
    const int qid = b * NQB + q;
    const float qx = p1[(size_t)qid * 3 + 0];
    const float qy = p1[(size_t)qid * 3 + 1];
    const float qz = p1[(size_t)qid * 3 + 2];
    const float qq = (qx * qx + qy * qy) + qz * qz;
    const int cqx = min(7, (int)(qx * 8.0f));
    const int cqy = min(7, (int)(qy * 8.0f));
    const int cqz = min(7, (int)(qz * 8.0f));

    float b0 = 3.0e38f, b1 = 3.0e38f, b2 = 3.0e38f;
    int i0 = 0x7fffffff, i1 = 0x7fffffff, i2 = 0x7fffffff;

    int n = 0;
    for (int dz = -1; dz <= 1; ++dz)
        for (int dy = -1; dy <= 1; ++dy)
            for (int dx = -1; dx <= 1; ++dx, ++n) {
                if (half ? (n < 14) : (n >= 14)) continue;   // 14 / 13 cell split
                const int cz = cqz + dz, cy = cqy + dy, cx = cqx + dx;
                if (((unsigned)cz | (unsigned)cy | (unsigned)cx) > 7u) continue;
                const int cell = (cz << 6) | (cy << 3) | cx;
                const int ks = st[cell], ke = st[cell + 1];
                for (int k = ks; k < ke; ++k) {
                    const float4 P = pb[k];
                    const int si = ib[k];
                    const float dot = fmaf(qz, P.z, fmaf(qy, P.y, qx * P.x));
                    const float d = fmaf(-2.0f, dot, qq + P.w);
                    ins3(d, si, b0, b1, b2, i0, i1, i2);
                }
            }

    if (half) {
        mD[lq * 3 + 0] = b0; mD[lq * 3 + 1] = b1; mD[lq * 3 + 2] = b2;
        mI[lq * 3 + 0] = i0; mI[lq * 3 + 1] = i1; mI[lq * 3 + 2] = i2;
    }
    __syncthreads();
    if (!half) {
#pragma unroll
        for (int r = 0; r < 3; ++r)
            ins3(mD[lq * 3 + r], mI[lq * 3 + r], b0, b1, b2, i0, i1, i2);

        if (!(b2 < GRID_FAIL_R2)) i0 = -1;     // sentinel: final brute-forces

        const float r0 = 1.0f / (fmaxf(b0, 0.0f) + 1e-8f);
        const float r1 = 1.0f / (fmaxf(b1, 0.0f) + 1e-8f);
        const float r2 = 1.0f / (fmaxf(b2, 0.0f) + 1e-8f);
        const float rs = (r0 + r1) + r2;
        idx_out[(size_t)qid * 3 + 0] = i0;
        idx_out[(size_t)qid * 3 + 1] = i1;
        idx_out[(size_t)qid * 3 + 2] = i2;
        w_out[(size_t)qid * 3 + 0] = r0 / rs;
        w_out[(size_t)qid * 3 + 1] = r1 / rs;
        w_out[(size_t)qid * 3 + 2] = r2 / rs;
    }
}

// ---------------------------------------------------------------------------
// MEGA dispatch: KNN + both GEMMs concurrently (all mutually independent).
// blocks 0..511: KNN (VALU-heavy, ~3 KB LDS) — scheduled FIRST so its waves
// fill the gemm blocks' latency bubbles (gemm: MfmaUtil 6%, VALU 6%, 94%
// stall).  blocks 512..1535: gemm1 (BM=128, KD=256).  1536..2047: gemm2
// (BM=64, KD=512).  Uniform 20 KB LDS.
// ---------------------------------------------------------------------------
__global__ __launch_bounds__(256)
void mega_kernel(const float* __restrict__ feat1, const short* __restrict__ WT1,
                 const float* __restrict__ b1, float* __restrict__ Y1,
                 float* __restrict__ pS1, float* __restrict__ pQ1,
                 const float* __restrict__ feat2, const short* __restrict__ WT2,
                 const float* __restrict__ b2, float* __restrict__ Y2,
                 float* __restrict__ pS2, float* __restrict__ pQ2,
                 const float* __restrict__ point1, const float4* __restrict__ sortedP,
                 const unsigned short* __restrict__ sIdx16,
                 const int* __restrict__ starts_p, const unsigned short* __restrict__ qlist,
                 int* __restrict__ idxb, float* __restrict__ wb)
{
    __shared__ short As[2][128 * ASTRIDE];    // 20 KB (knn uses 3 KB of it)
    const int id = blockIdx.x;
    if (id < 512) {
        float* mD = (float*)&As[0][0];                    // 1.5 KB
        int*   mI = (int*)((char*)&As[0][0] + 1536);      // 1.5 KB
        knn_body(id, point1, sortedP, sIdx16, starts_p, qlist, idxb, wb, mD, mI);
    } else if (id < 1536) {
        const int j = id - 512;
        gemm_body<128>(j >> 1, j & 1, feat1, WT1, b1, Y1, pS1, pQ1, 256,
                       As[0], As[1]);
    } else {
        const int j = id - 1536;
        gemm_body<64>(j >> 1, j & 1, feat2, WT2, b2, Y2, pS2, pQ2, 512,
                      As[0], As[1]);
    }
}

// ---------------------------------------------------------------------------
// Partial-stat reduce: blocks 0..15 sum BN1's 1024 partial rows (64 each),
// blocks 16..23 sum BN2's 512 rows (64 each); ~16/8 atomics per address.
// ---------------------------------------------------------------------------
__global__ __launch_bounds__(256)
void stat_reduce_kernel(const float* __restrict__ pS1, const float* __restrict__ pQ1,
                        const float* __restrict__ pS2, const float* __restrict__ pQ2,
                        float* __restrict__ stats)
{
    const int c = threadIdx.x;
    const bool two = blockIdx.x >= 16;
    const float* pS = two ? pS2 : pS1;
    const float* pQ = two ? pQ2 : pQ1;
    const int r0 = (two ? (blockIdx.x - 16) : blockIdx.x) * 64;
    float s = 0.f, q = 0.f;
    for (int r = r0; r < r0 + 64; ++r) {
        s += pS[(size_t)r * CC + c];
        q += pQ[(size_t)r * CC + c];
    }
    float* st = stats + (two ? 512 : 0);
    atomicAdd(&st[c], s);
    atomicAdd(&st[256 + c], q);
}

// ---------------------------------------------------------------------------
// Finalize BN constants: a = g*rsqrt(var+eps), c = beta - a*mu
// ---------------------------------------------------------------------------
__global__ __launch_bounds__(512)
void finalize_kernel(const float* __restrict__ sums,
                     const float* __restrict__ g1, const float* __restrict__ be1,
                     const float* __restrict__ g2, const float* __restrict__ be2,
                     float* __restrict__ ac)
{
    const int t = threadIdx.x;           // 0..511
    const int c = t & 255;
    const int which = t >> 8;            // 0: BN1, 1: BN2
    const float* s = sums + which * 512;
    const double n = which ? (double)N2R : (double)N1R;
    const double mu = (double)s[c] / n;
    const double var = (double)s[c + 256] / n - mu * mu;
    const float g  = which ? g2[c]  : g1[c];
    const float be = which ? be2[c] : be1[c];
    const double a  = (double)g / sqrt(var + 1e-5);
    const double cv = (double)be - a * mu;
    ac[which * 512 + c]       = (float)a;
    ac[which * 512 + 256 + c] = (float)cv;
}

// ---------------------------------------------------------------------------
// Final: out[r][c] = relu(a1*Y1+c1) + sum_k w_k * relu(a2*Y2[idx_k]+c2).
// Rows in qlist (cell-sorted) order for gather locality.  Rows flagged with
// idx[0] == -1 (~0.5%, grid-KNN boundary failures) are brute-forced inline
// by their wave (same ins3+butterfly as the old knn_bf kernel).
// ---------------------------------------------------------------------------
__global__ __launch_bounds__(256)
void final_kernel(float* __restrict__ Y1out,
                  const float* __restrict__ Y2raw,
                  const float* __restrict__ ac,        // a1,c1,a2,c2 (256 each)
                  const int* __restrict__ idx, const float* __restrict__ w,
                  const unsigned short* __restrict__ qlist,
                  const float* __restrict__ p1, const float4* __restrict__ paug)
{
#pragma clang fp contract(off)
    const int slot = blockIdx.x * 4 + (threadIdx.x >> 6);
    const int b = slot >> 14;
    const int r = b * NQB + qlist[slot];     // cell-sorted row
    const int cg = threadIdx.x & 63;

    const int* ir = idx + (size_t)r * 3;
    int i0 = ir[0], i1 = ir[1], i2 = ir[2];
    float w0, w1, w2;
    if (i0 >= 0) {
        const float* wr = w + (size_t)r * 3;
        w0 = wr[0]; w1 = wr[1]; w2 = wr[2];
    } else {
        // wave-uniform brute force over the batch's 4096 points
        const float qx = p1[(size_t)r * 3 + 0];
        const float qy = p1[(size_t)r * 3 + 1];
        const float qz = p1[(size_t)r * 3 + 2];
        const float qq = (qx * qx + qy * qy) + qz * qz;
        float b0 = 3.0e38f, b1 = 3.0e38f, b2 = 3.0e38f;
        i0 = 0x7fffffff; i1 = 0x7fffffff; i2 = 0x7fffffff;
        const float4* pb = paug + (size_t)b * NPB;
        for (int j = cg; j < NPB; j += 64) {
            const float4 P = pb[j];
            const float dot = fmaf(qz, P.z, fmaf(qy, P.y, qx * P.x));
            const float d = fmaf(-2.0f, dot, qq + P.w);
            ins3(d, j, b0, b1, b2, i0, i1, i2);
        }
        for (int m = 1; m < 64; m <<= 1) {
            const float c0 = __shfl_xor(b0, m), c1 = __shfl_xor(b1, m), c2 = __shfl_xor(b2, m);
            const int j0 = __shfl_xor(i0, m), j1 = __shfl_xor(i1, m), j2 = __shfl_xor(i2, m);
            ins3(c0, j0, b0, b1, b2, i0, i1, i2);
            ins3(c1, j1, b0, b1, b2, i0, i1, i2);
            ins3(c2, j2, b0, b1, b2, i0, i1, i2);
        }
        const float r0 = 1.0f / (fmaxf(b0, 0.0f) + 1e-8f);
        const float r1 = 1.0f / (fmaxf(b1, 0.0f) + 1e-8f);
        const float r2 = 1.0f / (fmaxf(b2, 0.0f) + 1e-8f);
        const float rs = (r0 + r1) + r2;
        w0 = r0 / rs; w1 = r1 / rs; w2 = r2 / rs;
    }

    v4f a1 = *(const v4f*)(ac + cg * 4);
    v4f c1 = *(const v4f*)(ac + 256 + cg * 4);
    v4f a2 = *(const v4f*)(ac + 512 + cg * 4);
    v4f c2 = *(const v4f*)(ac + 768 + cg * 4);
    v4f y = *(const v4f*)(Y1out + (size_t)r * CC + cg * 4);
    v4f s;
#pragma unroll
    for (int j = 0; j < 4; ++j)
        s[j] = fmaxf(fmaf(a1[j], y[j], c1[j]), 0.f);

    const int   id3[3] = { i0, i1, i2 };
    const float wk3[3] = { w0, w1, w2 };
#pragma unroll
    for (int k = 0; k < 3; ++k) {
        const float wk = wk3[k];
        v4f g = *(const v4f*)(Y2raw + ((size_t)(b * NPB + id3[k])) * CC + cg * 4);
#pragma unroll
        for (int j = 0; j < 4; ++j) {
            const float gv = fmaxf(fmaf(a2[j], g[j], c2[j]), 0.f);   // == bnrelu
            s[j] = fmaf(wk, gv, s[j]);
        }
    }
    *(v4f*)(Y1out + (size_t)r * CC + cg * 4) = s;
}

// ---------------------------------------------------------------------------
extern "C" void kernel_launch(void* const* d_in, const int* in_sizes, int n_in,
                              void* d_out, int out_size, void* d_ws, size_t ws_size,
                              hipStream_t stream)
{
    const float* point1 = (const float*)d_in[0];
    const float* feat1  = (const float*)d_in[1];
    const float* point2 = (const float*)d_in[2];
    const float* feat2  = (const float*)d_in[3];
    const float* W1     = (const float*)d_in[4];
    const float* b1     = (const float*)d_in[5];
    const float* g1     = (const float*)d_in[6];
    const float* beta1  = (const float*)d_in[7];
    const float* W2     = (const float*)d_in[8];
    const float* b2     = (const float*)d_in[9];
    const float* g2     = (const float*)d_in[10];
    const float* beta2  = (const float*)d_in[11];

    float* Y1 = (float*)d_out;                            // 64 MB (reused as output)

    char* ws = (char*)d_ws;
    float*          Y2       = (float*)ws;                                   // 16 MB (raw, BN fused in final)
    float*          stats    = (float*)(ws + (size_t)16777216);              // 4 KB
    int*            counts_p = (int*)  (ws + (size_t)16781312);              // 8 KB
    int*            counts_q = (int*)  (ws + (size_t)16789504);              // 8 KB
    int*            cursors_p= (int*)  (ws + (size_t)16801792);              // 8 KB
    int*            cursors_q= (int*)  (ws + (size_t)16809984);              // 8 KB
    int*            starts_p = (int*)  (ws + (size_t)16818176);              // 8.2 KB
    float*          ac       = (float*)(ws + (size_t)16826624);              // 4 KB
    unsigned short* sIdx16   = (unsigned short*)(ws + (size_t)16830720);     // 32 KB
    unsigned short* qlist    = (unsigned short*)(ws + (size_t)16863488);     // 128 KB
    float4*         sortedP  = (float4*)(ws + (size_t)17256704);             // 256 KB
    int*            idxb     = (int*)  (ws + (size_t)17518848);              // 768 KB
    float*          wb       = (float*)(ws + (size_t)18305280);              // 768 KB
    short*          WT1      = (short*)(ws + (size_t)19091712);              // 128 KB
    short*          WT2      = (short*)(ws + (size_t)19222784);              // 256 KB
    float4*         paug     = (float4*)(ws + (size_t)19484928);             // 256 KB
    float*          partS1   = (float*)(ws + (size_t)19747072);              // 1 MB (1024 x 256)
    float*          partQ1   = (float*)(ws + (size_t)21844224);              // 1 MB
    float*          partS2   = (float*)(ws + (size_t)23941376);              // 512 KB (512 x 256)
    float*          partQ2   = (float*)(ws + (size_t)24465664);              // 512 KB

    // zero: stats (4KB) + counts_p (8KB) + counts_q (8KB) (+pad)
    hipMemsetAsync(stats, 0, 24576, stream);

    // Merged prep: W transposes + paug + histograms; prefix; scatters
    prep_kernel<<<1088, 256, 0, stream>>>(W1, W2, WT1, WT2, point2, point1,
                                          paug, counts_p, counts_q);
    prefix_kernel<<<1, 512, 0, stream>>>(counts_p, cursors_p, starts_p, counts_q, cursors_q);
    scatter_kernel<<<320, 256, 0, stream>>>(paug, point1, cursors_p, cursors_q,
                                            sortedP, sIdx16, qlist);

    // MEGA: KNN (512) + gemm1 BM=128 (1024) + gemm2 BM=64 (512), one dispatch
    mega_kernel<<<2048, 256, 0, stream>>>(feat1, WT1, b1, Y1, partS1, partQ1,
                                          feat2, WT2, b2, Y2, partS2, partQ2,
                                          point1, sortedP, sIdx16, starts_p,
                                          qlist, idxb, wb);

    // Partial reduce (16 blocks BN1 + 8 blocks BN2) then finalize
    stat_reduce_kernel<<<24, 256, 0, stream>>>(partS1, partQ1, partS2, partQ2, stats);
    finalize_kernel<<<1, 512, 0, stream>>>(stats, g1, beta1, g2, beta2, ac);

    // out = relu(bn(Y1)) + weighted gather of relu(bn(Y2)), cell-sorted order;
    // flagged rows brute-forced inline
    final_kernel<<<N1R / 4, 256, 0, stream>>>(Y1, Y2, ac, idxb, wb, qlist,
                                              point1, paug);
}